// Round 1
// baseline (357.290 us; speedup 1.0000x reference)
//
#include <hip/hip_runtime.h>
#include <hip/hip_cooperative_groups.h>
#include <math.h>

// ---------------------------------------------------------------------------
// Strict2_5DLoss — 3-level triangle detection loss, forward only.
//
// R5 -> R6: single cooperative kernel, zero memsets.
//  - R5 had 3 graph nodes (memset 94KB -> mega -> finalize). The memset
//    existed only to zero the dedup flag bitmask + atomic banks.
//  - Now: phase A (selection + dense base sum) writes per-item result slots
//    with PLAIN stores (no init needed) and dumps selected indices to a
//    global list; grid.sync(); phase B dedups per (b,level) in an LDS bitmap
//    (zeroed in LDS, free) and computes the obj correction; grid.sync();
//    phase C (block 0) reduces all slots and writes the scalar loss.
//  - Removes: memset node, finalize node, 49K global atomicOr, bank atomics.
// ---------------------------------------------------------------------------

#define K_SEL 64
#define CAP   1536
#define NBLK  512           // 2 work-items each -> 1024 items
#define NITEM 1024
#define NRED  256
#define TOTAL_PIX 688128.0f // 8*(65536+16384+4096)

typedef unsigned long long u64;

__device__ __forceinline__ float softplus_f(float x) {
    return fmaxf(x, 0.0f) + log1pf(expf(-fabsf(x)));
}

__device__ __forceinline__ float seg_dist(float px, float py,
                                          float x1, float y1, float x2, float y2) {
    float vx = x2 - x1, vy = y2 - y1;
    float wx = px - x1, wy = py - y1;
    float t = (wx * vx + wy * vy) / (vx * vx + vy * vy + 1e-9f);
    t = fminf(fmaxf(t, 0.0f), 1.0f);
    float dx = px - (x1 + t * vx), dy = py - (y1 + t * vy);
    return sqrtf(dx * dx + dy * dy + 1e-12f);
}

__device__ __forceinline__ bool tri_mask_dist(float px, float py,
    float Ax, float Ay, float Bx, float By, float Cx, float Cy, float* dout) {
    float d1 = (px - Bx) * (Ay - By) - (Ax - Bx) * (py - By);
    float d2 = (px - Cx) * (By - Cy) - (Bx - Cx) * (py - Cy);
    float d3 = (px - Ax) * (Cy - Ay) - (Cx - Ax) * (py - Ay);
    bool has_neg = (d1 < 0.f) || (d2 < 0.f) || (d3 < 0.f);
    bool has_pos = (d1 > 0.f) || (d2 > 0.f) || (d3 > 0.f);
    bool inside = !(has_neg && has_pos);
    float dist = fminf(seg_dist(px, py, Ax, Ay, Bx, By),
                 fminf(seg_dist(px, py, Bx, By, Cx, Cy),
                       seg_dist(px, py, Cx, Cy, Ax, Ay)));
    *dout = dist;
    return inside || (dist <= 3.0f);
}

__global__ __launch_bounds__(256, 2)
void s25d_coop(const float* __restrict__ reg0, const float* __restrict__ obj0, const float* __restrict__ cls0,
               const float* __restrict__ reg1, const float* __restrict__ obj1, const float* __restrict__ cls1,
               const float* __restrict__ reg2, const float* __restrict__ obj2, const float* __restrict__ cls2,
               const float* __restrict__ gt,
               float4* __restrict__ selSums,   // [NITEM] {reg, cls, sn, base}
               int*    __restrict__ selList,   // [NITEM * K_SEL]
               float*  __restrict__ grpS,      // [24 * 16] 64B-padded {corr, pos_now}
               float*  __restrict__ out) {
    const int bid = blockIdx.x;
    const int tid = threadIdx.x;
    const int lane = tid & 63;
    const int wv = tid >> 6;

    __shared__ union {
        struct { unsigned hi[CAP]; unsigned lo[CAP]; } k;  // phase A keys
        unsigned bitmap[2048];                             // phase B dedup (8 KB)
    } u;
    __shared__ int scnt;
    __shared__ int hist[256];
    __shared__ int wtot[4];
    __shared__ int s_d, s_below, s_cnt;
    __shared__ int sel_hw[K_SEL];
    __shared__ int sel_n;
    __shared__ float red4[4];
    __shared__ float s_sn[32];
    __shared__ float cred[4][6];

    // ============================ PHASE A ============================
    for (int it = 0; it < 2; ++it) {
        const int item = bid * 2 + it;      // pairs (lvl0,lvl1) or (lvl2,red)
        const int type = item & 3;          // 0,1,2 = selection levels; 3 = dense
        const int unit = item >> 2;         // 0..255
        __syncthreads();                    // protect shared reuse across items

        if (type < 3) {
            // ---------------- per-(level, b, g) selection ----------------
            const int level = type;
            const int b = unit >> 5, g = unit & 31;

            const float* regp; const float* clsp;
            int Ws, log2Ws; float stride;
            if (level == 0)      { regp = reg0; clsp = cls0; Ws = 256; log2Ws = 8; stride =  8.f; }
            else if (level == 1) { regp = reg1; clsp = cls1; Ws = 128; log2Ws = 7; stride = 16.f; }
            else                 { regp = reg2; clsp = cls2; Ws =  64; log2Ws = 6; stride = 32.f; }
            const int HW = Ws * Ws;

            const float* tri = gt + (size_t)((b * 32 + g) * 3) * 2;
            const float Ax = tri[0], Ay = tri[1], Bx = tri[2], By = tri[3], Cx = tri[4], Cy = tri[5];

            if (tid == 0) { scnt = 0; sel_n = 0; }
            __syncthreads();

            // conservative bbox (+ETA, plus one-cell slack each side)
            float minx = fminf(Ax, fminf(Bx, Cx)) - 3.0f;
            float maxx = fmaxf(Ax, fmaxf(Bx, Cx)) + 3.0f;
            float miny = fminf(Ay, fminf(By, Cy)) - 3.0f;
            float maxy = fmaxf(Ay, fmaxf(By, Cy)) + 3.0f;
            int ix_lo = max(0,      (int)floorf(minx / stride - 0.5f));
            int ix_hi = min(Ws - 1, (int)ceilf (maxx / stride - 0.5f));
            int iy_lo = max(0,      (int)floorf(miny / stride - 0.5f));
            int iy_hi = min(Ws - 1, (int)ceilf (maxy / stride - 0.5f));
            int nx = ix_hi - ix_lo + 1, ny = iy_hi - iy_lo + 1;
            int ncells = (nx > 0 && ny > 0) ? nx * ny : 0;

            // ---- candidate collection (wave-aggregated LDS push) ----
            for (int base = 0; base < ncells; base += 256) {
                int c = base + tid;
                bool pred = false; unsigned dbits = 0; int idx = 0;
                if (c < ncells) {
                    int ix = ix_lo + (c % nx);
                    int iy = iy_lo + (c / nx);
                    float px = (ix + 0.5f) * stride, py = (iy + 0.5f) * stride;
                    float d;
                    if (tri_mask_dist(px, py, Ax, Ay, Bx, By, Cx, Cy, &d)) {
                        pred = true;
                        dbits = __float_as_uint(d);      // d > 0 -> monotonic bits
                        idx = (iy << log2Ws) | ix;
                    }
                }
                u64 m = __ballot(pred);
                if (m) {
                    int rank = __popcll(m & ((1ull << lane) - 1));
                    int total = __popcll(m);
                    int fl = __ffsll((unsigned long long)m) - 1;
                    int bs = 0;
                    if (lane == fl) bs = atomicAdd(&scnt, total);
                    bs = __shfl(bs, fl, 64);
                    if (pred) {
                        int slot = bs + rank;
                        if (slot < CAP) { u.k.hi[slot] = dbits; u.k.lo[slot] = (unsigned)idx; }
                    }
                }
            }
            __syncthreads();
            const int  cnt = scnt;
            const bool ovf = (cnt > CAP);

            // ---- exact 64-bit radix select of the K-th smallest key ----
            u64 threshold = ~0ull;           // cnt<=K: everything selected
            if (cnt > K_SEL) {
                u64 prefix = 0;
                int need = K_SEL;
                const int lim = ovf ? ncells : cnt;
                for (int shift = 56; shift >= 0; shift -= 8) {
                    hist[tid] = 0;
                    __syncthreads();
                    for (int base = 0; base < lim; base += 256) {
                        int c = base + tid;
                        if (c < lim) {
                            bool has = false; u64 key = 0;
                            if (!ovf) {
                                key = ((u64)u.k.hi[c] << 32) | u.k.lo[c];
                                has = true;
                            } else {
                                int ix = ix_lo + (c % nx);
                                int iy = iy_lo + (c / nx);
                                float px = (ix + 0.5f) * stride, py = (iy + 0.5f) * stride;
                                float d;
                                if (tri_mask_dist(px, py, Ax, Ay, Bx, By, Cx, Cy, &d)) {
                                    key = ((u64)__float_as_uint(d) << 32) | (unsigned)((iy << log2Ws) | ix);
                                    has = true;
                                }
                            }
                            if (has && (shift == 56 || (key >> (shift + 8)) == prefix))
                                atomicAdd(&hist[(int)((key >> shift) & 255)], 1);
                        }
                    }
                    __syncthreads();
                    // 256-bin inclusive scan: shfl within wave, 4 wave totals via LDS
                    int v = hist[tid];
                    int x = v;
#pragma unroll
                    for (int dlt = 1; dlt < 64; dlt <<= 1) {
                        int y = __shfl_up(x, dlt, 64);
                        if (lane >= dlt) x += y;
                    }
                    if (lane == 63) wtot[wv] = x;
                    __syncthreads();
                    int pre = 0;
                    for (int i = 0; i < wv; ++i) pre += wtot[i];
                    int cum = x + pre;
                    int below = cum - v;
                    if (cum >= need && below < need) { s_d = tid; s_below = below; s_cnt = v; }
                    __syncthreads();
                    int d = s_d, bl = s_below, bc = s_cnt;
                    prefix = (prefix << 8) | (unsigned)d;
                    if (bl + bc == need) {   // pivot bin count == remaining need -> exact
                        threshold = (prefix << shift) | (shift ? ((1ull << shift) - 1) : 0ull);
                        break;
                    }
                    need -= bl;
                    // keys unique -> terminates by shift==0
                }
            }
            __syncthreads();

            // ---- compact selected (<= 64) indices into LDS ----
            {
                const int lim = ovf ? ncells : cnt;
                for (int base = 0; base < lim; base += 256) {
                    int c = base + tid;
                    bool take = false; int hw = 0;
                    if (c < lim) {
                        if (!ovf) {
                            unsigned lo = u.k.lo[c];
                            u64 key = ((u64)u.k.hi[c] << 32) | lo;
                            take = (key <= threshold); hw = (int)lo;
                        } else {
                            int ix = ix_lo + (c % nx);
                            int iy = iy_lo + (c / nx);
                            float px = (ix + 0.5f) * stride, py = (iy + 0.5f) * stride;
                            float d;
                            if (tri_mask_dist(px, py, Ax, Ay, Bx, By, Cx, Cy, &d)) {
                                hw = (iy << log2Ws) | ix;
                                u64 key = ((u64)__float_as_uint(d) << 32) | (unsigned)hw;
                                take = (key <= threshold);
                            }
                        }
                    }
                    u64 m = __ballot(take);
                    if (m) {
                        int rank = __popcll(m & ((1ull << lane) - 1));
                        int total = __popcll(m);
                        int fl = __ffsll((unsigned long long)m) - 1;
                        int bs = 0;
                        if (lane == fl) bs = atomicAdd(&sel_n, total);
                        bs = __shfl(bs, fl, 64);
                        if (take) {
                            int slot = bs + rank;
                            if (slot < K_SEL) sel_hw[slot] = hw;
                        }
                    }
                }
            }
            __syncthreads();
            const int sn = min(sel_n, K_SEL);

            // ---- contribution: tid<sn, all loads parallel; dump sel list ----
            float my_reg = 0.f, my_cls = 0.f;
            if (tid < sn) {
                int hw = sel_hw[tid];
                selList[item * K_SEL + tid] = hw;         // for phase-B dedup
                int ix = hw & (Ws - 1), iy = hw >> log2Ws;
                float ax = (ix + 0.5f) * stride, ay = (iy + 0.5f) * stride;
                int pix = b * HW + hw;

                float xc = clsp[pix];
                float p[6];
#pragma unroll
                for (int ch = 0; ch < 6; ++ch) {
                    float vv = regp[(size_t)(b * 6 + ch) * HW + hw];
                    p[ch] = fminf(fmaxf(vv, -64.f), 64.f);
                }
                my_cls = softplus_f(-xc);

                float inv = 1.0f / stride;
                float g0x = (Ax - ax) * inv, g0y = (Ay - ay) * inv;
                float g1x = (Bx - ax) * inv, g1y = (By - ay) * inv;
                float g2x = (Cx - ax) * inv, g2y = (Cy - ay) * inv;
                float p0 = (p[0] - g0x) * (p[0] - g0x) + (p[1] - g0y) * (p[1] - g0y);
                float d00 = sqrtf((p[2] - g1x) * (p[2] - g1x) + (p[3] - g1y) * (p[3] - g1y));
                float d01 = sqrtf((p[2] - g2x) * (p[2] - g2x) + (p[3] - g2y) * (p[3] - g2y));
                float d10 = sqrtf((p[4] - g1x) * (p[4] - g1x) + (p[5] - g1y) * (p[5] - g1y));
                float d11 = sqrtf((p[4] - g2x) * (p[4] - g2x) + (p[5] - g2y) * (p[5] - g2y));
                float cd = fminf(d00, d01) + fminf(d10, d11) + fminf(d00, d10) + fminf(d01, d11);
                my_reg = p0 + cd;
            }

            // wave-0-only reduce (selected lanes are all in wave 0)
            if (wv == 0) {
#pragma unroll
                for (int dlt = 32; dlt > 0; dlt >>= 1) {
                    my_reg += __shfl_down(my_reg, dlt, 64);
                    my_cls += __shfl_down(my_cls, dlt, 64);
                }
                if (lane == 0)
                    selSums[item] = make_float4(my_reg, my_cls, (float)sn, 0.f);
            }
        } else {
            // ---------------- dense obj softplus base sum (float4) ----------------
            const int rb = unit;
            const float4* arrs[3] = { (const float4*)obj0, (const float4*)obj1, (const float4*)obj2 };
            const int    lens4[3] = { 131072, 32768, 8192 };
            float s = 0.f;
            for (int a = 0; a < 3; ++a) {
                const float4* p = arrs[a]; int n4 = lens4[a];
                for (int i = rb * 256 + tid; i < n4; i += NRED * 256) {
                    float4 v = p[i];
                    s += softplus_f(v.x) + softplus_f(v.y) + softplus_f(v.z) + softplus_f(v.w);
                }
            }
#pragma unroll
            for (int dlt = 32; dlt > 0; dlt >>= 1) s += __shfl_down(s, dlt, 64);
            if (lane == 0) red4[wv] = s;
            __syncthreads();
            if (tid == 0)
                selSums[item] = make_float4(0.f, 0.f, 0.f, red4[0] + red4[1] + red4[2] + red4[3]);
        }
    }

    __threadfence();
    cooperative_groups::this_grid().sync();
    __threadfence();

    // ============================ PHASE B ============================
    // 24 groups = (b, level): dedup selected pixels in an LDS bitmap,
    // accumulate obj correction (1.2*sp(-x) - sp(x)) and unique count.
    if (bid < 24) {
        const int b = bid / 3, level = bid % 3;
        const float* objp; int HW;
        if (level == 0)      { objp = obj0; HW = 65536; }
        else if (level == 1) { objp = obj1; HW = 16384; }
        else                 { objp = obj2; HW = 4096;  }
        const int words = HW >> 5;

        for (int i = tid; i < words; i += 256) u.bitmap[i] = 0u;
        if (tid < 32) {
            int item = ((b * 32 + tid) << 2) | level;
            s_sn[tid] = selSums[item].z;
        }
        __syncthreads();

        float corr = 0.f, cntf = 0.f;
        for (int j = tid; j < 32 * K_SEL; j += 256) {
            int g = j >> 6, k = j & 63;
            if (k < (int)s_sn[g]) {
                int item = ((b * 32 + g) << 2) | level;
                int hw = selList[item * K_SEL + k];
                unsigned bit = 1u << (hw & 31);
                unsigned old = atomicOr(&u.bitmap[hw >> 5], bit);
                if (!(old & bit)) {
                    float xo = objp[b * HW + hw];
                    corr += 1.2f * softplus_f(-xo) - softplus_f(xo);
                    cntf += 1.f;
                }
            }
        }
#pragma unroll
        for (int dlt = 32; dlt > 0; dlt >>= 1) {
            corr += __shfl_down(corr, dlt, 64);
            cntf += __shfl_down(cntf, dlt, 64);
        }
        if (lane == 0) { cred[wv][0] = corr; cred[wv][1] = cntf; }
        __syncthreads();
        if (tid == 0) {
            grpS[bid * 16 + 0] = cred[0][0] + cred[1][0] + cred[2][0] + cred[3][0];
            grpS[bid * 16 + 1] = cred[0][1] + cred[1][1] + cred[2][1] + cred[3][1];
        }
    }

    __threadfence();
    cooperative_groups::this_grid().sync();
    __threadfence();

    // ============================ PHASE C ============================
    if (bid == 0) {
        float a0 = 0.f, a1 = 0.f, a2 = 0.f, a3 = 0.f;   // reg, cls, pos, base
        for (int i = tid; i < NITEM; i += 256) {
            float4 v = selSums[i];
            a0 += v.x; a1 += v.y; a2 += v.z; a3 += v.w;
        }
        float c0 = 0.f, c1 = 0.f;                        // corr, pos_now
        if (tid < 24) { c0 = grpS[tid * 16 + 0]; c1 = grpS[tid * 16 + 1]; }
#pragma unroll
        for (int dlt = 32; dlt > 0; dlt >>= 1) {
            a0 += __shfl_down(a0, dlt, 64);
            a1 += __shfl_down(a1, dlt, 64);
            a2 += __shfl_down(a2, dlt, 64);
            a3 += __shfl_down(a3, dlt, 64);
            c0 += __shfl_down(c0, dlt, 64);
            c1 += __shfl_down(c1, dlt, 64);
        }
        if (lane == 0) {
            cred[wv][0] = a0; cred[wv][1] = a1; cred[wv][2] = a2;
            cred[wv][3] = a3; cred[wv][4] = c0; cred[wv][5] = c1;
        }
        __syncthreads();
        if (tid == 0) {
            float reg_s = cred[0][0] + cred[1][0] + cred[2][0] + cred[3][0];
            float cls_s = cred[0][1] + cred[1][1] + cred[2][1] + cred[3][1];
            float pos   = cred[0][2] + cred[1][2] + cred[2][2] + cred[3][2];
            float base  = cred[0][3] + cred[1][3] + cred[2][3] + cred[3][3];
            float corr  = cred[0][4] + cred[1][4] + cred[2][4] + cred[3][4];
            float pnow  = cred[0][5] + cred[1][5] + cred[2][5] + cred[3][5];
            float obj_s = base + corr;
            float neg = TOTAL_PIX - pnow;
            float pos_eps = fmaxf(pos, 1.0f);
            float total = reg_s / pos_eps + obj_s / (pos_eps + fmaxf(neg, 1.0f)) + cls_s / pos_eps;
            out[0] = isfinite(total) ? total : 0.0f;
        }
    }
}

extern "C" void kernel_launch(void* const* d_in, const int* in_sizes, int n_in,
                              void* d_out, int out_size, void* d_ws, size_t ws_size,
                              hipStream_t stream) {
    const float* reg0 = (const float*)d_in[0];
    const float* obj0 = (const float*)d_in[1];
    const float* cls0 = (const float*)d_in[2];
    const float* reg1 = (const float*)d_in[3];
    const float* obj1 = (const float*)d_in[4];
    const float* cls1 = (const float*)d_in[5];
    const float* reg2 = (const float*)d_in[6];
    const float* obj2 = (const float*)d_in[7];
    const float* cls2 = (const float*)d_in[8];
    const float* gt   = (const float*)d_in[9];

    // ws layout (nothing needs pre-clearing — every slot is written before read):
    //   [0, 16384)           float4 selSums[1024]
    //   [16384, 278528)      int    selList[1024*64]
    //   [278528, 280064)     float  grpS[24*16] (64B padded per group)
    float4* selSums = (float4*)d_ws;
    int*    selList = (int*)((char*)d_ws + 16384);
    float*  grpS    = (float*)((char*)d_ws + 16384 + 262144);
    float*  outp    = (float*)d_out;

    void* args[] = { &reg0, &obj0, &cls0, &reg1, &obj1, &cls1, &reg2, &obj2, &cls2, &gt,
                     &selSums, &selList, &grpS, &outp };
    hipLaunchCooperativeKernel((const void*)s25d_coop, dim3(NBLK), dim3(256),
                               args, 0, stream);
}

// Round 2
// 171.494 us; speedup vs baseline: 2.0834x; 2.0834x over previous
//
#include <hip/hip_runtime.h>
#include <math.h>

// ---------------------------------------------------------------------------
// Strict2_5DLoss — 3-level triangle detection loss, forward only.
//
// R6 post-mortem: cooperative grid.sync cost 260 µs of pure stall (VALUBusy
// 1.5%) — reverted. R6 also revealed the real budget: harness reset overhead
// (poison fills + restore dispatches) is ~90 µs/iter; our kernels were only
// ~3-6 µs of R5's 90.4. So R7 = R5 structure, minus one graph node:
//
// R5 -> R7: finalize folded into mega via last-block-done pattern.
//  - Each block: bank atomicAdds -> __threadfence -> atomicAdd(doneCnt).
//  - The 1024th block to finish reduces the 64 banks inline (agent-scope
//    atomic loads: a plain load could hit a stale XCD-local L2 line cached
//    at memset time, since other XCDs' atomics update the coherence point)
//    and writes the scalar loss. Removes the 1-block finalize dispatch.
// ---------------------------------------------------------------------------

#define K_SEL 64
#define CAP   1536
#define NBLK_TOT 1024       // 256 units x {lvl0, lvl1, lvl2, reduction}
#define NBLK_RED 256
#define NBANK 64
#define BANK_STRIDE 32      // floats (128 B per bank)
// per-bank counter slots: 0=reg_s 1=cls_s 2=obj_corr 3=obj_base 4=pos 5=pos_now
#define TOTAL_PIX 688128.0f // 8*(65536+16384+4096)

typedef unsigned long long u64;

__device__ __forceinline__ float softplus_f(float x) {
    return fmaxf(x, 0.0f) + log1pf(expf(-fabsf(x)));
}

__device__ __forceinline__ float seg_dist(float px, float py,
                                          float x1, float y1, float x2, float y2) {
    float vx = x2 - x1, vy = y2 - y1;
    float wx = px - x1, wy = py - y1;
    float t = (wx * vx + wy * vy) / (vx * vx + vy * vy + 1e-9f);
    t = fminf(fmaxf(t, 0.0f), 1.0f);
    float dx = px - (x1 + t * vx), dy = py - (y1 + t * vy);
    return sqrtf(dx * dx + dy * dy + 1e-12f);
}

__device__ __forceinline__ bool tri_mask_dist(float px, float py,
    float Ax, float Ay, float Bx, float By, float Cx, float Cy, float* dout) {
    float d1 = (px - Bx) * (Ay - By) - (Ax - Bx) * (py - By);
    float d2 = (px - Cx) * (By - Cy) - (Bx - Cx) * (py - Cy);
    float d3 = (px - Ax) * (Cy - Ay) - (Cx - Ax) * (py - Ay);
    bool has_neg = (d1 < 0.f) || (d2 < 0.f) || (d3 < 0.f);
    bool has_pos = (d1 > 0.f) || (d2 > 0.f) || (d3 > 0.f);
    bool inside = !(has_neg && has_pos);
    float dist = fminf(seg_dist(px, py, Ax, Ay, Bx, By),
                 fminf(seg_dist(px, py, Bx, By, Cx, Cy),
                       seg_dist(px, py, Cx, Cy, Ax, Ay)));
    *dout = dist;
    return inside || (dist <= 3.0f);
}

__global__ __launch_bounds__(256)
void s25d_mega(const float* __restrict__ reg0, const float* __restrict__ obj0, const float* __restrict__ cls0,
               const float* __restrict__ reg1, const float* __restrict__ obj1, const float* __restrict__ cls1,
               const float* __restrict__ reg2, const float* __restrict__ obj2, const float* __restrict__ cls2,
               const float* __restrict__ gt,
               float* banks, unsigned* flags, unsigned* doneCnt, float* out) {
    const int bid = blockIdx.x;
    const int tid = threadIdx.x;
    const int lane = tid & 63;
    const int wv = tid >> 6;
    const int type = bid & 3;     // 0,1,2 = selection levels; 3 = dense reduction
    const int unit = bid >> 2;    // 0..255
    float* bank = banks + (size_t)(bid & (NBANK - 1)) * BANK_STRIDE;

    __shared__ unsigned skey_hi[CAP];
    __shared__ unsigned skey_lo[CAP];
    __shared__ int scnt;
    __shared__ int hist[256];
    __shared__ int wtot[4];
    __shared__ int s_d, s_below, s_cnt;
    __shared__ int sel_hw[K_SEL];
    __shared__ int sel_n;
    __shared__ float red4[4];
    __shared__ int s_last;

    if (type < 3) {
        // -------------------- per-(level, b, g) selection block --------------------
        const int level = type;
        const int b = unit >> 5, g = unit & 31;

        const float* regp; const float* objp; const float* clsp;
        int Ws, log2Ws, flagBase; float stride;
        if (level == 0)      { regp = reg0; objp = obj0; clsp = cls0; Ws = 256; log2Ws = 8; stride =  8.f; flagBase = 0; }
        else if (level == 1) { regp = reg1; objp = obj1; clsp = cls1; Ws = 128; log2Ws = 7; stride = 16.f; flagBase = 16384; }
        else                 { regp = reg2; objp = obj2; clsp = cls2; Ws =  64; log2Ws = 6; stride = 32.f; flagBase = 20480; }
        const int HW = Ws * Ws;

        const float* tri = gt + (size_t)((b * 32 + g) * 3) * 2;
        const float Ax = tri[0], Ay = tri[1], Bx = tri[2], By = tri[3], Cx = tri[4], Cy = tri[5];

        if (tid == 0) { scnt = 0; sel_n = 0; }
        __syncthreads();

        // conservative bbox (+ETA, plus one-cell slack each side)
        float minx = fminf(Ax, fminf(Bx, Cx)) - 3.0f;
        float maxx = fmaxf(Ax, fmaxf(Bx, Cx)) + 3.0f;
        float miny = fminf(Ay, fminf(By, Cy)) - 3.0f;
        float maxy = fmaxf(Ay, fmaxf(By, Cy)) + 3.0f;
        int ix_lo = max(0,      (int)floorf(minx / stride - 0.5f));
        int ix_hi = min(Ws - 1, (int)ceilf (maxx / stride - 0.5f));
        int iy_lo = max(0,      (int)floorf(miny / stride - 0.5f));
        int iy_hi = min(Ws - 1, (int)ceilf (maxy / stride - 0.5f));
        int nx = ix_hi - ix_lo + 1, ny = iy_hi - iy_lo + 1;
        int ncells = (nx > 0 && ny > 0) ? nx * ny : 0;

        // ---- candidate collection (wave-aggregated LDS push) ----
        for (int base = 0; base < ncells; base += 256) {
            int c = base + tid;
            bool pred = false; unsigned dbits = 0; int idx = 0;
            if (c < ncells) {
                int ix = ix_lo + (c % nx);
                int iy = iy_lo + (c / nx);
                float px = (ix + 0.5f) * stride, py = (iy + 0.5f) * stride;
                float d;
                if (tri_mask_dist(px, py, Ax, Ay, Bx, By, Cx, Cy, &d)) {
                    pred = true;
                    dbits = __float_as_uint(d);      // d > 0 -> monotonic bits
                    idx = (iy << log2Ws) | ix;
                }
            }
            u64 m = __ballot(pred);
            if (m) {
                int rank = __popcll(m & ((1ull << lane) - 1));
                int total = __popcll(m);
                int fl = __ffsll((unsigned long long)m) - 1;
                int bs = 0;
                if (lane == fl) bs = atomicAdd(&scnt, total);
                bs = __shfl(bs, fl, 64);
                if (pred) {
                    int slot = bs + rank;
                    if (slot < CAP) { skey_hi[slot] = dbits; skey_lo[slot] = (unsigned)idx; }
                }
            }
        }
        __syncthreads();
        const int  cnt = scnt;
        const bool ovf = (cnt > CAP);

        // ---- exact 64-bit radix select of the K-th smallest key ----
        u64 threshold = ~0ull;           // cnt<=K: everything selected
        if (cnt > K_SEL) {
            u64 prefix = 0;
            int need = K_SEL;
            const int lim = ovf ? ncells : cnt;
            for (int shift = 56; shift >= 0; shift -= 8) {
                hist[tid] = 0;
                __syncthreads();
                for (int base = 0; base < lim; base += 256) {
                    int c = base + tid;
                    if (c < lim) {
                        bool has = false; u64 key = 0;
                        if (!ovf) {
                            key = ((u64)skey_hi[c] << 32) | skey_lo[c];
                            has = true;
                        } else {
                            int ix = ix_lo + (c % nx);
                            int iy = iy_lo + (c / nx);
                            float px = (ix + 0.5f) * stride, py = (iy + 0.5f) * stride;
                            float d;
                            if (tri_mask_dist(px, py, Ax, Ay, Bx, By, Cx, Cy, &d)) {
                                key = ((u64)__float_as_uint(d) << 32) | (unsigned)((iy << log2Ws) | ix);
                                has = true;
                            }
                        }
                        if (has && (shift == 56 || (key >> (shift + 8)) == prefix))
                            atomicAdd(&hist[(int)((key >> shift) & 255)], 1);
                    }
                }
                __syncthreads();
                // 256-bin inclusive scan: shfl within wave, 4 wave totals via LDS
                int v = hist[tid];
                int x = v;
#pragma unroll
                for (int dlt = 1; dlt < 64; dlt <<= 1) {
                    int y = __shfl_up(x, dlt, 64);
                    if (lane >= dlt) x += y;
                }
                if (lane == 63) wtot[wv] = x;
                __syncthreads();
                int pre = 0;
                for (int i = 0; i < wv; ++i) pre += wtot[i];
                int cum = x + pre;
                int below = cum - v;
                if (cum >= need && below < need) { s_d = tid; s_below = below; s_cnt = v; }
                __syncthreads();
                int d = s_d, bl = s_below, bc = s_cnt;
                prefix = (prefix << 8) | (unsigned)d;
                if (bl + bc == need) {   // pivot bin count == remaining need -> exact
                    threshold = (prefix << shift) | (shift ? ((1ull << shift) - 1) : 0ull);
                    break;
                }
                need -= bl;
                // keys unique -> terminates by shift==0
            }
        }
        __syncthreads();

        // ---- compact selected (<= 64) indices into LDS ----
        {
            const int lim = ovf ? ncells : cnt;
            for (int base = 0; base < lim; base += 256) {
                int c = base + tid;
                bool take = false; int hw = 0;
                if (c < lim) {
                    if (!ovf) {
                        unsigned lo = skey_lo[c];
                        u64 key = ((u64)skey_hi[c] << 32) | lo;
                        take = (key <= threshold); hw = (int)lo;
                    } else {
                        int ix = ix_lo + (c % nx);
                        int iy = iy_lo + (c / nx);
                        float px = (ix + 0.5f) * stride, py = (iy + 0.5f) * stride;
                        float d;
                        if (tri_mask_dist(px, py, Ax, Ay, Bx, By, Cx, Cy, &d)) {
                            hw = (iy << log2Ws) | ix;
                            u64 key = ((u64)__float_as_uint(d) << 32) | (unsigned)hw;
                            take = (key <= threshold);
                        }
                    }
                }
                u64 m = __ballot(take);
                if (m) {
                    int rank = __popcll(m & ((1ull << lane) - 1));
                    int total = __popcll(m);
                    int fl = __ffsll((unsigned long long)m) - 1;
                    int bs = 0;
                    if (lane == fl) bs = atomicAdd(&sel_n, total);
                    bs = __shfl(bs, fl, 64);
                    if (take) {
                        int slot = bs + rank;
                        if (slot < K_SEL) sel_hw[slot] = hw;
                    }
                }
            }
        }
        __syncthreads();
        const int sn = min(sel_n, K_SEL);

        // ---- one-shot contribution: tid<sn, all memory ops parallel ----
        float my_reg = 0.f, my_cls = 0.f, my_corr = 0.f, my_first = 0.f;
        if (tid < sn) {
            int hw = sel_hw[tid];
            int ix = hw & (Ws - 1), iy = hw >> log2Ws;
            float ax = (ix + 0.5f) * stride, ay = (iy + 0.5f) * stride;
            int pix = b * HW + hw;

            int word = flagBase + (pix >> 5);
            unsigned bit = 1u << (pix & 31);
            unsigned old = atomicOr(&flags[word], bit);   // independent of loads below
            float xo = objp[pix];
            float xc = clsp[pix];
            float p[6];
#pragma unroll
            for (int ch = 0; ch < 6; ++ch) {
                float vv = regp[(size_t)(b * 6 + ch) * HW + hw];
                p[ch] = fminf(fmaxf(vv, -64.f), 64.f);
            }
            float first = (old & bit) ? 0.f : 1.f;
            my_first = first;
            my_corr = first * (1.2f * softplus_f(-xo) - softplus_f(xo));
            my_cls = softplus_f(-xc);

            float inv = 1.0f / stride;
            float g0x = (Ax - ax) * inv, g0y = (Ay - ay) * inv;
            float g1x = (Bx - ax) * inv, g1y = (By - ay) * inv;
            float g2x = (Cx - ax) * inv, g2y = (Cy - ay) * inv;
            float p0 = (p[0] - g0x) * (p[0] - g0x) + (p[1] - g0y) * (p[1] - g0y);
            float d00 = sqrtf((p[2] - g1x) * (p[2] - g1x) + (p[3] - g1y) * (p[3] - g1y));
            float d01 = sqrtf((p[2] - g2x) * (p[2] - g2x) + (p[3] - g2y) * (p[3] - g2y));
            float d10 = sqrtf((p[4] - g1x) * (p[4] - g1x) + (p[5] - g1y) * (p[5] - g1y));
            float d11 = sqrtf((p[4] - g2x) * (p[4] - g2x) + (p[5] - g2y) * (p[5] - g2y));
            float cd = fminf(d00, d01) + fminf(d10, d11) + fminf(d00, d10) + fminf(d01, d11);
            my_reg = p0 + cd;
        }

        // wave-0-only reduce (selected lanes are all in wave 0)
        if (wv == 0) {
#pragma unroll
            for (int dlt = 32; dlt > 0; dlt >>= 1) {
                my_reg   += __shfl_down(my_reg, dlt, 64);
                my_cls   += __shfl_down(my_cls, dlt, 64);
                my_corr  += __shfl_down(my_corr, dlt, 64);
                my_first += __shfl_down(my_first, dlt, 64);
            }
            if (lane == 0 && sn > 0) {
                atomicAdd(&bank[0], my_reg);
                atomicAdd(&bank[1], my_cls);
                atomicAdd(&bank[2], my_corr);
                atomicAdd(&bank[4], (float)sn);
                atomicAdd(&bank[5], my_first);
            }
        }
    } else {
        // -------------------- dense obj softplus base sum (float4) --------------------
        const int rb = unit;
        const float4* arrs[3] = { (const float4*)obj0, (const float4*)obj1, (const float4*)obj2 };
        const int    lens4[3] = { 131072, 32768, 8192 };
        float s = 0.f;
        for (int a = 0; a < 3; ++a) {
            const float4* p = arrs[a]; int n4 = lens4[a];
            for (int i = rb * 256 + tid; i < n4; i += NBLK_RED * 256) {
                float4 v = p[i];
                s += softplus_f(v.x) + softplus_f(v.y) + softplus_f(v.z) + softplus_f(v.w);
            }
        }
#pragma unroll
        for (int dlt = 32; dlt > 0; dlt >>= 1) s += __shfl_down(s, dlt, 64);
        if (lane == 0) red4[wv] = s;
        __syncthreads();
        if (tid == 0) atomicAdd(&bank[3], red4[0] + red4[1] + red4[2] + red4[3]);
    }

    // -------------------- last-block-done inline finalize --------------------
    __syncthreads();
    __threadfence();                       // release: bank atomics before doneCnt
    if (tid == 0) {
        unsigned t = atomicAdd(doneCnt, 1u);
        s_last = (t == NBLK_TOT - 1) ? 1 : 0;
    }
    __syncthreads();
    if (s_last && wv == 0) {
        __threadfence();                   // acquire side
        const float* bk = banks + (size_t)lane * BANK_STRIDE;
        // agent-scope atomic loads: plain loads could hit a stale XCD-local
        // L2 line cached at memset time (other XCDs' atomicAdds update the
        // device coherence point, not this XCD's L2).
        float reg_s   = __hip_atomic_load(&bk[0], __ATOMIC_RELAXED, __HIP_MEMORY_SCOPE_AGENT);
        float cls_s   = __hip_atomic_load(&bk[1], __ATOMIC_RELAXED, __HIP_MEMORY_SCOPE_AGENT);
        float corr    = __hip_atomic_load(&bk[2], __ATOMIC_RELAXED, __HIP_MEMORY_SCOPE_AGENT);
        float base    = __hip_atomic_load(&bk[3], __ATOMIC_RELAXED, __HIP_MEMORY_SCOPE_AGENT);
        float pos     = __hip_atomic_load(&bk[4], __ATOMIC_RELAXED, __HIP_MEMORY_SCOPE_AGENT);
        float pos_now = __hip_atomic_load(&bk[5], __ATOMIC_RELAXED, __HIP_MEMORY_SCOPE_AGENT);
#pragma unroll
        for (int dlt = 32; dlt > 0; dlt >>= 1) {
            reg_s   += __shfl_down(reg_s, dlt, 64);
            cls_s   += __shfl_down(cls_s, dlt, 64);
            corr    += __shfl_down(corr, dlt, 64);
            base    += __shfl_down(base, dlt, 64);
            pos     += __shfl_down(pos, dlt, 64);
            pos_now += __shfl_down(pos_now, dlt, 64);
        }
        if (lane == 0) {
            float obj_s = base + corr;
            float neg = TOTAL_PIX - pos_now;
            float pos_eps = fmaxf(pos, 1.0f);
            float total = reg_s / pos_eps + obj_s / (pos_eps + fmaxf(neg, 1.0f)) + cls_s / pos_eps;
            out[0] = isfinite(total) ? total : 0.0f;
        }
    }
}

extern "C" void kernel_launch(void* const* d_in, const int* in_sizes, int n_in,
                              void* d_out, int out_size, void* d_ws, size_t ws_size,
                              hipStream_t stream) {
    const float* reg0 = (const float*)d_in[0];
    const float* obj0 = (const float*)d_in[1];
    const float* cls0 = (const float*)d_in[2];
    const float* reg1 = (const float*)d_in[3];
    const float* obj1 = (const float*)d_in[4];
    const float* cls1 = (const float*)d_in[5];
    const float* reg2 = (const float*)d_in[6];
    const float* obj2 = (const float*)d_in[7];
    const float* cls2 = (const float*)d_in[8];
    const float* gt   = (const float*)d_in[9];

    // ws layout: [0, 8192)            64 accumulator banks x 128 B
    //            [8192, 8192+86016)   flag bitmask (lvl0:16384w, lvl1:4096w, lvl2:1024w)
    //            [94208, 94212)       doneCnt
    float*    banks   = (float*)d_ws;
    unsigned* flags   = (unsigned*)((char*)d_ws + NBANK * BANK_STRIDE * sizeof(float));
    unsigned* doneCnt = (unsigned*)((char*)d_ws + NBANK * BANK_STRIDE * sizeof(float) + 21504 * 4);
    size_t clear_bytes = NBANK * BANK_STRIDE * sizeof(float) + 21504 * 4 + 4;
    hipMemsetAsync(d_ws, 0, clear_bytes, stream);

    s25d_mega<<<dim3(NBLK_TOT), dim3(256), 0, stream>>>(
        reg0, obj0, cls0, reg1, obj1, cls1, reg2, obj2, cls2, gt,
        banks, flags, doneCnt, (float*)d_out);
}

// Round 3
// 90.396 us; speedup vs baseline: 3.9525x; 1.8971x over previous
//
#include <hip/hip_runtime.h>
#include <math.h>

// ---------------------------------------------------------------------------
// Strict2_5DLoss — 3-level triangle detection loss, forward only.
//
// R7 post-mortem: folding finalize via __threadfence() cost +47 µs — the
// fence lowers to buffer_wbl2 (XCD L2 writeback) x1024 blocks, plus 1024
// contended atomics on one doneCnt line. But R7 fixed the budget model:
// two 42 µs harness poison fills are ~84 µs of every iteration; our R5
// pipeline was only ~6 µs (memset + mega ~3 µs + finalize + node gaps).
//
// R8 = R5 selection logic, ONE kernel node, zero memsets, MALL-only fencing:
//  - All cross-block data are device-scope atomics (complete at the MALL
//    coherence point) -> ordering needs only s_waitcnt vmcnt(0), never wbl2.
//  - 64 reduction blocks zero banks+flags+done counters in-kernel (agent
//    atomic stores), then each writes a per-zeroer MAGIC signal word
//    (store-once: needs no init itself). Blocks gate on all-64 signals
//    (wave64 ballot spin) just before their first flags atomicOr; zeroing
//    (~1 µs) finishes before gates are reached, so spins are ~free.
//    All 1024 blocks are co-resident (<= capacity) -> no deadlock.
//  - Finalize folded into the last block via two-level done counters
//    (done1[64] x16 blocks, then done2) -> max ~80 serialized atomics.
// ---------------------------------------------------------------------------

#define K_SEL 64
#define CAP   1536
#define NBLK_TOT 1024       // 256 units x {lvl0, lvl1, lvl2, reduction}
#define NBLK_RED 256
#define NZERO 64
#define NBANK 64
#define BANK_STRIDE 32      // floats (128 B per bank)
// per-bank counter slots: 0=reg_s 1=cls_s 2=obj_corr 3=obj_base 4=pos 5=pos_now
#define TOTAL_PIX 688128.0f // 8*(65536+16384+4096)
#define ZMAGIC 0x600DF00Du

// ws word layout:
//   [0, 2048)        banks (64 x 32 floats)
//   [2048, 23552)    flags bitmask (lvl0:16384w, lvl1:4096w, lvl2:1024w)
//   [23552, 23616)   done1[64]
//   [23632]          done2
//   [23680, 23744)   zsig[64]  (NOT zeroed; store-once magic)
#define ZERO_WORDS 23633    // zero through done2 inclusive

typedef unsigned long long u64;

__device__ __forceinline__ float softplus_f(float x) {
    return fmaxf(x, 0.0f) + log1pf(expf(-fabsf(x)));
}

__device__ __forceinline__ float seg_dist(float px, float py,
                                          float x1, float y1, float x2, float y2) {
    float vx = x2 - x1, vy = y2 - y1;
    float wx = px - x1, wy = py - y1;
    float t = (wx * vx + wy * vy) / (vx * vx + vy * vy + 1e-9f);
    t = fminf(fmaxf(t, 0.0f), 1.0f);
    float dx = px - (x1 + t * vx), dy = py - (y1 + t * vy);
    return sqrtf(dx * dx + dy * dy + 1e-12f);
}

__device__ __forceinline__ bool tri_mask_dist(float px, float py,
    float Ax, float Ay, float Bx, float By, float Cx, float Cy, float* dout) {
    float d1 = (px - Bx) * (Ay - By) - (Ax - Bx) * (py - By);
    float d2 = (px - Cx) * (By - Cy) - (Bx - Cx) * (py - Cy);
    float d3 = (px - Ax) * (Cy - Ay) - (Cx - Ax) * (py - Ay);
    bool has_neg = (d1 < 0.f) || (d2 < 0.f) || (d3 < 0.f);
    bool has_pos = (d1 > 0.f) || (d2 > 0.f) || (d3 > 0.f);
    bool inside = !(has_neg && has_pos);
    float dist = fminf(seg_dist(px, py, Ax, Ay, Bx, By),
                 fminf(seg_dist(px, py, Bx, By, Cx, Cy),
                       seg_dist(px, py, Cx, Cy, Ax, Ay)));
    *dout = dist;
    return inside || (dist <= 3.0f);
}

__device__ __forceinline__ void zgate_spin(unsigned* zsig, int lane) {
    // wave0-wide spin: lane i watches zsig[i]; agent-scope loads read MALL.
    unsigned v;
    do {
        v = __hip_atomic_load(&zsig[lane], __ATOMIC_RELAXED, __HIP_MEMORY_SCOPE_AGENT);
        if (__ballot(v == ZMAGIC) == ~0ull) break;
        __builtin_amdgcn_s_sleep(1);
    } while (true);
}

__global__ __launch_bounds__(256)
void s25d_mega(const float* __restrict__ reg0, const float* __restrict__ obj0, const float* __restrict__ cls0,
               const float* __restrict__ reg1, const float* __restrict__ obj1, const float* __restrict__ cls1,
               const float* __restrict__ reg2, const float* __restrict__ obj2, const float* __restrict__ cls2,
               const float* __restrict__ gt,
               unsigned* ws, float* out) {
    const int bid = blockIdx.x;
    const int tid = threadIdx.x;
    const int lane = tid & 63;
    const int wv = tid >> 6;
    const int type = bid & 3;     // 0,1,2 = selection levels; 3 = dense reduction
    const int unit = bid >> 2;    // 0..255

    float*    banks = (float*)ws;
    unsigned* flags = ws + 2048;
    unsigned* done1 = ws + 23552;
    unsigned* done2 = ws + 23632;
    unsigned* zsig  = ws + 23680;
    float* bank = banks + (size_t)(bid & (NBANK - 1)) * BANK_STRIDE;

    __shared__ unsigned skey_hi[CAP];
    __shared__ unsigned skey_lo[CAP];
    __shared__ int scnt;
    __shared__ int hist[256];
    __shared__ int wtot[4];
    __shared__ int s_d, s_below, s_cnt;
    __shared__ int sel_hw[K_SEL];
    __shared__ int sel_n;
    __shared__ float red4[4];
    __shared__ int s_last;

    if (type < 3) {
        // -------------------- per-(level, b, g) selection block --------------------
        const int level = type;
        const int b = unit >> 5, g = unit & 31;

        const float* regp; const float* objp; const float* clsp;
        int Ws, log2Ws, flagBase; float stride;
        if (level == 0)      { regp = reg0; objp = obj0; clsp = cls0; Ws = 256; log2Ws = 8; stride =  8.f; flagBase = 0; }
        else if (level == 1) { regp = reg1; objp = obj1; clsp = cls1; Ws = 128; log2Ws = 7; stride = 16.f; flagBase = 16384; }
        else                 { regp = reg2; objp = obj2; clsp = cls2; Ws =  64; log2Ws = 6; stride = 32.f; flagBase = 20480; }
        const int HW = Ws * Ws;

        const float* tri = gt + (size_t)((b * 32 + g) * 3) * 2;
        const float Ax = tri[0], Ay = tri[1], Bx = tri[2], By = tri[3], Cx = tri[4], Cy = tri[5];

        if (tid == 0) { scnt = 0; sel_n = 0; }
        __syncthreads();

        // conservative bbox (+ETA, plus one-cell slack each side)
        float minx = fminf(Ax, fminf(Bx, Cx)) - 3.0f;
        float maxx = fmaxf(Ax, fmaxf(Bx, Cx)) + 3.0f;
        float miny = fminf(Ay, fminf(By, Cy)) - 3.0f;
        float maxy = fmaxf(Ay, fmaxf(By, Cy)) + 3.0f;
        int ix_lo = max(0,      (int)floorf(minx / stride - 0.5f));
        int ix_hi = min(Ws - 1, (int)ceilf (maxx / stride - 0.5f));
        int iy_lo = max(0,      (int)floorf(miny / stride - 0.5f));
        int iy_hi = min(Ws - 1, (int)ceilf (maxy / stride - 0.5f));
        int nx = ix_hi - ix_lo + 1, ny = iy_hi - iy_lo + 1;
        int ncells = (nx > 0 && ny > 0) ? nx * ny : 0;

        // ---- candidate collection (wave-aggregated LDS push) ----
        for (int base = 0; base < ncells; base += 256) {
            int c = base + tid;
            bool pred = false; unsigned dbits = 0; int idx = 0;
            if (c < ncells) {
                int ix = ix_lo + (c % nx);
                int iy = iy_lo + (c / nx);
                float px = (ix + 0.5f) * stride, py = (iy + 0.5f) * stride;
                float d;
                if (tri_mask_dist(px, py, Ax, Ay, Bx, By, Cx, Cy, &d)) {
                    pred = true;
                    dbits = __float_as_uint(d);      // d > 0 -> monotonic bits
                    idx = (iy << log2Ws) | ix;
                }
            }
            u64 m = __ballot(pred);
            if (m) {
                int rank = __popcll(m & ((1ull << lane) - 1));
                int total = __popcll(m);
                int fl = __ffsll((unsigned long long)m) - 1;
                int bs = 0;
                if (lane == fl) bs = atomicAdd(&scnt, total);
                bs = __shfl(bs, fl, 64);
                if (pred) {
                    int slot = bs + rank;
                    if (slot < CAP) { skey_hi[slot] = dbits; skey_lo[slot] = (unsigned)idx; }
                }
            }
        }
        __syncthreads();
        const int  cnt = scnt;
        const bool ovf = (cnt > CAP);

        // ---- exact 64-bit radix select of the K-th smallest key ----
        u64 threshold = ~0ull;           // cnt<=K: everything selected
        if (cnt > K_SEL) {
            u64 prefix = 0;
            int need = K_SEL;
            const int lim = ovf ? ncells : cnt;
            for (int shift = 56; shift >= 0; shift -= 8) {
                hist[tid] = 0;
                __syncthreads();
                for (int base = 0; base < lim; base += 256) {
                    int c = base + tid;
                    if (c < lim) {
                        bool has = false; u64 key = 0;
                        if (!ovf) {
                            key = ((u64)skey_hi[c] << 32) | skey_lo[c];
                            has = true;
                        } else {
                            int ix = ix_lo + (c % nx);
                            int iy = iy_lo + (c / nx);
                            float px = (ix + 0.5f) * stride, py = (iy + 0.5f) * stride;
                            float d;
                            if (tri_mask_dist(px, py, Ax, Ay, Bx, By, Cx, Cy, &d)) {
                                key = ((u64)__float_as_uint(d) << 32) | (unsigned)((iy << log2Ws) | ix);
                                has = true;
                            }
                        }
                        if (has && (shift == 56 || (key >> (shift + 8)) == prefix))
                            atomicAdd(&hist[(int)((key >> shift) & 255)], 1);
                    }
                }
                __syncthreads();
                // 256-bin inclusive scan: shfl within wave, 4 wave totals via LDS
                int v = hist[tid];
                int x = v;
#pragma unroll
                for (int dlt = 1; dlt < 64; dlt <<= 1) {
                    int y = __shfl_up(x, dlt, 64);
                    if (lane >= dlt) x += y;
                }
                if (lane == 63) wtot[wv] = x;
                __syncthreads();
                int pre = 0;
                for (int i = 0; i < wv; ++i) pre += wtot[i];
                int cum = x + pre;
                int below = cum - v;
                if (cum >= need && below < need) { s_d = tid; s_below = below; s_cnt = v; }
                __syncthreads();
                int d = s_d, bl = s_below, bc = s_cnt;
                prefix = (prefix << 8) | (unsigned)d;
                if (bl + bc == need) {   // pivot bin count == remaining need -> exact
                    threshold = (prefix << shift) | (shift ? ((1ull << shift) - 1) : 0ull);
                    break;
                }
                need -= bl;
                // keys unique -> terminates by shift==0
            }
        }
        __syncthreads();

        // ---- compact selected (<= 64) indices into LDS ----
        {
            const int lim = ovf ? ncells : cnt;
            for (int base = 0; base < lim; base += 256) {
                int c = base + tid;
                bool take = false; int hw = 0;
                if (c < lim) {
                    if (!ovf) {
                        unsigned lo = skey_lo[c];
                        u64 key = ((u64)skey_hi[c] << 32) | lo;
                        take = (key <= threshold); hw = (int)lo;
                    } else {
                        int ix = ix_lo + (c % nx);
                        int iy = iy_lo + (c / nx);
                        float px = (ix + 0.5f) * stride, py = (iy + 0.5f) * stride;
                        float d;
                        if (tri_mask_dist(px, py, Ax, Ay, Bx, By, Cx, Cy, &d)) {
                            hw = (iy << log2Ws) | ix;
                            u64 key = ((u64)__float_as_uint(d) << 32) | (unsigned)hw;
                            take = (key <= threshold);
                        }
                    }
                }
                u64 m = __ballot(take);
                if (m) {
                    int rank = __popcll(m & ((1ull << lane) - 1));
                    int total = __popcll(m);
                    int fl = __ffsll((unsigned long long)m) - 1;
                    int bs = 0;
                    if (lane == fl) bs = atomicAdd(&sel_n, total);
                    bs = __shfl(bs, fl, 64);
                    if (take) {
                        int slot = bs + rank;
                        if (slot < K_SEL) sel_hw[slot] = hw;
                    }
                }
            }
        }
        __syncthreads();
        const int sn = min(sel_n, K_SEL);

        // ---- gate: all zeroing done (zeroing finishes ~1 µs in; we arrive
        //      after several µs of selection work, so this rarely spins) ----
        if (wv == 0) zgate_spin(zsig, lane);
        __syncthreads();

        // ---- one-shot contribution: tid<sn, all memory ops parallel ----
        float my_reg = 0.f, my_cls = 0.f, my_corr = 0.f, my_first = 0.f;
        if (tid < sn) {
            int hw = sel_hw[tid];
            int ix = hw & (Ws - 1), iy = hw >> log2Ws;
            float ax = (ix + 0.5f) * stride, ay = (iy + 0.5f) * stride;
            int pix = b * HW + hw;

            int word = flagBase + (pix >> 5);
            unsigned bit = 1u << (pix & 31);
            unsigned old = atomicOr(&flags[word], bit);   // independent of loads below
            float xo = objp[pix];
            float xc = clsp[pix];
            float p[6];
#pragma unroll
            for (int ch = 0; ch < 6; ++ch) {
                float vv = regp[(size_t)(b * 6 + ch) * HW + hw];
                p[ch] = fminf(fmaxf(vv, -64.f), 64.f);
            }
            float first = (old & bit) ? 0.f : 1.f;
            my_first = first;
            my_corr = first * (1.2f * softplus_f(-xo) - softplus_f(xo));
            my_cls = softplus_f(-xc);

            float inv = 1.0f / stride;
            float g0x = (Ax - ax) * inv, g0y = (Ay - ay) * inv;
            float g1x = (Bx - ax) * inv, g1y = (By - ay) * inv;
            float g2x = (Cx - ax) * inv, g2y = (Cy - ay) * inv;
            float p0 = (p[0] - g0x) * (p[0] - g0x) + (p[1] - g0y) * (p[1] - g0y);
            float d00 = sqrtf((p[2] - g1x) * (p[2] - g1x) + (p[3] - g1y) * (p[3] - g1y));
            float d01 = sqrtf((p[2] - g2x) * (p[2] - g2x) + (p[3] - g2y) * (p[3] - g2y));
            float d10 = sqrtf((p[4] - g1x) * (p[4] - g1x) + (p[5] - g1y) * (p[5] - g1y));
            float d11 = sqrtf((p[4] - g2x) * (p[4] - g2x) + (p[5] - g2y) * (p[5] - g2y));
            float cd = fminf(d00, d01) + fminf(d10, d11) + fminf(d00, d10) + fminf(d01, d11);
            my_reg = p0 + cd;
        }

        // wave-0-only reduce (selected lanes are all in wave 0)
        if (wv == 0) {
#pragma unroll
            for (int dlt = 32; dlt > 0; dlt >>= 1) {
                my_reg   += __shfl_down(my_reg, dlt, 64);
                my_cls   += __shfl_down(my_cls, dlt, 64);
                my_corr  += __shfl_down(my_corr, dlt, 64);
                my_first += __shfl_down(my_first, dlt, 64);
            }
            if (lane == 0 && sn > 0) {
                atomicAdd(&bank[0], my_reg);
                atomicAdd(&bank[1], my_cls);
                atomicAdd(&bank[2], my_corr);
                atomicAdd(&bank[4], (float)sn);
                atomicAdd(&bank[5], my_first);
            }
        }
    } else {
        // -------------------- dense reduction block (+ zeroing duty) --------------------
        const int rb = unit;

        if (rb < NZERO) {
            // zero banks + flags + done counters: 23633 words over 64x256 threads
            for (int i = rb * 256 + tid; i < ZERO_WORDS; i += NZERO * 256)
                __hip_atomic_store(&ws[i], 0u, __ATOMIC_RELAXED, __HIP_MEMORY_SCOPE_AGENT);
            asm volatile("s_waitcnt vmcnt(0)" ::: "memory");
            if (tid == 0)
                __hip_atomic_store(&zsig[rb], ZMAGIC, __ATOMIC_RELAXED, __HIP_MEMORY_SCOPE_AGENT);
        }

        const float4* arrs[3] = { (const float4*)obj0, (const float4*)obj1, (const float4*)obj2 };
        const int    lens4[3] = { 131072, 32768, 8192 };
        float s = 0.f;
        for (int a = 0; a < 3; ++a) {
            const float4* p = arrs[a]; int n4 = lens4[a];
            for (int i = rb * 256 + tid; i < n4; i += NBLK_RED * 256) {
                float4 v = p[i];
                s += softplus_f(v.x) + softplus_f(v.y) + softplus_f(v.z) + softplus_f(v.w);
            }
        }
#pragma unroll
        for (int dlt = 32; dlt > 0; dlt >>= 1) s += __shfl_down(s, dlt, 64);
        if (lane == 0) red4[wv] = s;

        // gate before touching banks (banks must be zeroed by all 64 zeroers)
        if (wv == 0) zgate_spin(zsig, lane);
        __syncthreads();
        if (tid == 0) atomicAdd(&bank[3], red4[0] + red4[1] + red4[2] + red4[3]);
    }

    // -------------------- last-block-done inline finalize --------------------
    // All cross-block data are device-scope atomics (complete at MALL), so
    // ordering needs only vmcnt(0) — NOT __threadfence (which emits a
    // buffer_wbl2 L2-writeback; x1024 blocks that cost R7 +47 µs).
    __syncthreads();
    asm volatile("s_waitcnt vmcnt(0)" ::: "memory");
    if (tid == 0) {
        unsigned c = __hip_atomic_fetch_add(&done1[bid & 63], 1u,
                                            __ATOMIC_RELAXED, __HIP_MEMORY_SCOPE_AGENT);
        int lastflag = 0;
        if (c == 15u) {   // 16 blocks per done1 counter
            asm volatile("s_waitcnt vmcnt(0)" ::: "memory");
            unsigned cc = __hip_atomic_fetch_add(done2, 1u,
                                                 __ATOMIC_RELAXED, __HIP_MEMORY_SCOPE_AGENT);
            lastflag = (cc == 63u) ? 1 : 0;
        }
        s_last = lastflag;
    }
    __syncthreads();
    if (s_last && wv == 0) {
        const float* bk = banks + (size_t)lane * BANK_STRIDE;
        // agent-scope atomic loads: read the MALL-coherent values written by
        // other XCDs' atomicAdds (a plain load could hit a stale local line).
        float reg_s   = __hip_atomic_load(&bk[0], __ATOMIC_RELAXED, __HIP_MEMORY_SCOPE_AGENT);
        float cls_s   = __hip_atomic_load(&bk[1], __ATOMIC_RELAXED, __HIP_MEMORY_SCOPE_AGENT);
        float corr    = __hip_atomic_load(&bk[2], __ATOMIC_RELAXED, __HIP_MEMORY_SCOPE_AGENT);
        float base    = __hip_atomic_load(&bk[3], __ATOMIC_RELAXED, __HIP_MEMORY_SCOPE_AGENT);
        float pos     = __hip_atomic_load(&bk[4], __ATOMIC_RELAXED, __HIP_MEMORY_SCOPE_AGENT);
        float pos_now = __hip_atomic_load(&bk[5], __ATOMIC_RELAXED, __HIP_MEMORY_SCOPE_AGENT);
#pragma unroll
        for (int dlt = 32; dlt > 0; dlt >>= 1) {
            reg_s   += __shfl_down(reg_s, dlt, 64);
            cls_s   += __shfl_down(cls_s, dlt, 64);
            corr    += __shfl_down(corr, dlt, 64);
            base    += __shfl_down(base, dlt, 64);
            pos     += __shfl_down(pos, dlt, 64);
            pos_now += __shfl_down(pos_now, dlt, 64);
        }
        if (lane == 0) {
            float obj_s = base + corr;
            float neg = TOTAL_PIX - pos_now;
            float pos_eps = fmaxf(pos, 1.0f);
            float total = reg_s / pos_eps + obj_s / (pos_eps + fmaxf(neg, 1.0f)) + cls_s / pos_eps;
            out[0] = isfinite(total) ? total : 0.0f;
        }
    }
}

extern "C" void kernel_launch(void* const* d_in, const int* in_sizes, int n_in,
                              void* d_out, int out_size, void* d_ws, size_t ws_size,
                              hipStream_t stream) {
    const float* reg0 = (const float*)d_in[0];
    const float* obj0 = (const float*)d_in[1];
    const float* cls0 = (const float*)d_in[2];
    const float* reg1 = (const float*)d_in[3];
    const float* obj1 = (const float*)d_in[4];
    const float* cls1 = (const float*)d_in[5];
    const float* reg2 = (const float*)d_in[6];
    const float* obj2 = (const float*)d_in[7];
    const float* cls2 = (const float*)d_in[8];
    const float* gt   = (const float*)d_in[9];

    // single node: all workspace init happens in-kernel (see ws word layout).
    s25d_mega<<<dim3(NBLK_TOT), dim3(256), 0, stream>>>(
        reg0, obj0, cls0, reg1, obj1, cls1, reg2, obj2, cls2, gt,
        (unsigned*)d_ws, (float*)d_out);
}